// Round 1
// baseline (1886.033 us; speedup 1.0000x reference)
//
#include <hip/hip_runtime.h>
#include <math.h>

#define NL 28
#define DIM 1024
#define NHQ 16
#define NHKV 8
#define HDIM 128
#define NG 2
#define NFF 3072
#define NVOCAB 151936
#define NB 2
#define NPAST 1024
#define NPTOT 1025
#define EPSF 1e-6f
#define QKSCALE 0.08838834764831845f
#define LOGTHETA 13.815510557964274f

#define S1 8
#define S2 32
#define CHSZ 33
#define S3 8
#define S4 4
#define S5 8

// ws offsets (floats)
#define OFF_H   0
#define OFF_H1  2048
#define OFF_QKV 4096            // [S1][NB][4096]
#define OFF_AM  69632           // [NB][NHKV][NG][S2]
#define OFF_AL  70656
#define OFF_AO  71680           // [NB][NHKV][NG][S2][HDIM]
#define OFF_WO  202752          // [S3][NB][DIM]
#define OFF_G   219136          // [S4][NB][NFF]
#define OFF_U   243712
#define OFF_WD  268288          // [S5][NB][DIM]

#define PK_OFF ((size_t)NB*NVOCAB)
#define PV_OFF (PK_OFF + (size_t)NL*NB*NHKV*NPTOT*HDIM)

// ---------------- K1: rmsnorm(h) + QKV GEMV (split-K partials) ----------------
// grid (32 head-tasks, S1 d-splits), 256 threads
__global__ __launch_bounds__(256) void k1_qkv(
    const float* __restrict__ embeds, const float* __restrict__ Wq_,
    const float* __restrict__ Wk_, const float* __restrict__ Wv_,
    const float* __restrict__ ln1, float* __restrict__ ws, int l)
{
  int ht = blockIdx.x;   // 0..31: 0-15 q heads, 16-23 k heads, 24-31 v heads
  int s1 = blockIdx.y;   // 0..7 d-split
  int tid = threadIdx.x;
  __shared__ float sh[NB*DIM];
  __shared__ float red[512];
  float s0 = 0.f, sB = 0.f;
  for (int k = 0; k < 8; k++) {
    int idx = tid + k*256;
    int b = idx >> 10, d = idx & 1023;
    float v;
    if (l == 0) v = embeds[idx];
    else {
      v = ws[OFF_H1 + idx];
      #pragma unroll
      for (int s = 0; s < S5; s++) v += ws[OFF_WD + (s*NB + b)*DIM + d];
    }
    sh[idx] = v;
    if (b == 0) s0 += v*v; else sB += v*v;
  }
  red[tid] = s0; red[256+tid] = sB;
  __syncthreads();
  for (int off = 128; off > 0; off >>= 1) {
    if (tid < off) { red[tid] += red[tid+off]; red[256+tid] += red[256+tid+off]; }
    __syncthreads();
  }
  float r0 = rsqrtf(red[0]/DIM + EPSF);
  float r1 = rsqrtf(red[256]/DIM + EPSF);
  for (int k = 0; k < 8; k++) {
    int idx = tid + k*256;
    int b = idx >> 10, d = idx & 1023;
    float v = sh[idx];
    if (s1 == 0 && ht == 0) ws[OFF_H + idx] = v;   // materialize h_in for K4
    sh[idx] = v * (b ? r1 : r0) * ln1[l*DIM + d];
  }
  __syncthreads();
  const float* W; int O, colbase, slotbase;
  if (ht < 16)      { W = Wq_; O = NHQ*HDIM;  colbase = ht*HDIM;      slotbase = ht*HDIM; }
  else if (ht < 24) { W = Wk_; O = NHKV*HDIM; colbase = (ht-16)*HDIM; slotbase = 2048 + (ht-16)*HDIM; }
  else              { W = Wv_; O = NHKV*HDIM; colbase = (ht-24)*HDIM; slotbase = 3072 + (ht-24)*HDIM; }
  int o = tid & 127, ds = tid >> 7;
  int col = colbase + o;
  int dbase = s1*128 + ds*64;
  const float* Wp = W + (size_t)l*DIM*O + (size_t)dbase*O + col;
  float a0 = 0.f, a1 = 0.f;
  #pragma unroll 8
  for (int jj = 0; jj < 64; jj++) {
    float w = Wp[(size_t)jj*O];
    a0 += sh[dbase+jj]*w;
    a1 += sh[DIM+dbase+jj]*w;
  }
  red[tid] = a0; red[256+tid] = a1;
  __syncthreads();
  if (ds == 0) {
    float q0 = red[tid] + red[tid+128];
    float q1 = red[256+tid] + red[256+tid+128];
    ws[OFF_QKV + (s1*NB + 0)*4096 + slotbase + o] = q0;
    ws[OFF_QKV + (s1*NB + 1)*4096 + slotbase + o] = q1;
  }
}

// ---------------- K2: finalize q/k/v + qknorm + rope + KV copy + flash-decode --
// grid (S2 chunks, NHKV, NB), 256 threads = 4 waves
__global__ __launch_bounds__(256) void k2_attn(
    const float* __restrict__ pastK, const float* __restrict__ pastV,
    const int* __restrict__ posids, const float* __restrict__ qnw,
    const float* __restrict__ knw, float* __restrict__ out,
    float* __restrict__ ws, int l)
{
  int chunk = blockIdx.x, kv = blockIdx.y, b = blockIdx.z;
  int tid = threadIdx.x;
  int lane = tid & 63, wv = tid >> 6;
  int g = tid >> 7, o = tid & 127;
  __shared__ float pre[3*HDIM];
  __shared__ float qf[NG][HDIM], kf[HDIM], vf[HDIM];
  __shared__ float oc[NG][HDIM];
  __shared__ float wm[4][NG], wl[4][NG];
  __shared__ float red[256];

  int hq = kv*NG + g;
  float qraw = 0.f;
  #pragma unroll
  for (int s = 0; s < S1; s++) qraw += ws[OFF_QKV + (s*NB + b)*4096 + hq*HDIM + o];
  red[tid] = qraw*qraw;
  __syncthreads();
  for (int off = 64; off > 0; off >>= 1) {
    if (o < off) red[tid] += red[tid+off];
    __syncthreads();
  }
  float qr = rsqrtf(red[g*128]/HDIM + EPSF);
  float kraw = 0.f, vraw = 0.f;
  if (g == 0) {
    #pragma unroll
    for (int s = 0; s < S1; s++) kraw += ws[OFF_QKV + (s*NB + b)*4096 + 2048 + kv*HDIM + o];
  } else {
    #pragma unroll
    for (int s = 0; s < S1; s++) vraw += ws[OFF_QKV + (s*NB + b)*4096 + 3072 + kv*HDIM + o];
  }
  pre[g*HDIM + o] = qraw*qr*qnw[l*HDIM + o];
  __syncthreads();
  red[tid] = (g == 0) ? kraw*kraw : 0.f;
  __syncthreads();
  for (int off = 128; off > 0; off >>= 1) {
    if (tid < off) red[tid] += red[tid+off];
    __syncthreads();
  }
  float kr = rsqrtf(red[0]/HDIM + EPSF);
  if (g == 0) pre[2*HDIM + o] = kraw*kr*knw[l*HDIM + o];
  else vf[o] = vraw;
  __syncthreads();
  // rope
  float pos = (float)posids[b];
  int j = o & 63;
  float ang = pos * expf(-(2.0f*(float)j/(float)HDIM)*LOGTHETA);
  float sn, cs;
  sincosf(ang, &sn, &cs);
  {
    float qv = pre[g*HDIM + o];
    float qo = (o < 64) ? -pre[g*HDIM + o + 64] : pre[g*HDIM + o - 64];
    qf[g][o] = qv*cs + qo*sn;
    if (g == 0) {
      float kx = pre[2*HDIM + o];
      float ko = (o < 64) ? -pre[2*HDIM + o + 64] : pre[2*HDIM + o - 64];
      kf[o] = kx*cs + ko*sn;
    }
  }
  __syncthreads();

  int p0 = chunk*CHSZ;
  int p1 = (p0 + CHSZ < NPTOT) ? (p0 + CHSZ) : NPTOT;
  size_t pastbase = ((((size_t)l*NB + b)*NHKV + kv)*NPAST)*HDIM;
  size_t presbase = ((((size_t)l*NB + b)*NHKV + kv)*NPTOT)*HDIM;
  float q0a = qf[0][lane*2], q0b = qf[0][lane*2+1];
  float q1a = qf[1][lane*2], q1b = qf[1][lane*2+1];
  float m0 = -1e30f, m1 = -1e30f, l0 = 0.f, l1 = 0.f;
  float o0a = 0.f, o0b = 0.f, o1a = 0.f, o1b = 0.f;
  for (int p = p0 + wv; p < p1; p += 4) {
    float ka, kb, va, vb;
    if (p < NPAST) {
      float2 k2 = *(const float2*)(pastK + pastbase + (size_t)p*HDIM + lane*2);
      float2 v2 = *(const float2*)(pastV + pastbase + (size_t)p*HDIM + lane*2);
      ka = k2.x; kb = k2.y; va = v2.x; vb = v2.y;
    } else {
      ka = kf[lane*2]; kb = kf[lane*2+1];
      va = vf[lane*2]; vb = vf[lane*2+1];
    }
    *(float2*)(out + PK_OFF + presbase + (size_t)p*HDIM + lane*2) = make_float2(ka, kb);
    *(float2*)(out + PV_OFF + presbase + (size_t)p*HDIM + lane*2) = make_float2(va, vb);
    float d0 = q0a*ka + q0b*kb;
    float d1 = q1a*ka + q1b*kb;
    #pragma unroll
    for (int off = 32; off > 0; off >>= 1) {
      d0 += __shfl_xor(d0, off);
      d1 += __shfl_xor(d1, off);
    }
    d0 *= QKSCALE; d1 *= QKSCALE;
    float mn0 = fmaxf(m0, d0);
    float sc0 = __expf(m0 - mn0);
    float w0  = __expf(d0 - mn0);
    l0 = l0*sc0 + w0;
    o0a = o0a*sc0 + w0*va;
    o0b = o0b*sc0 + w0*vb;
    m0 = mn0;
    float mn1 = fmaxf(m1, d1);
    float sc1 = __expf(m1 - mn1);
    float w1  = __expf(d1 - mn1);
    l1 = l1*sc1 + w1;
    o1a = o1a*sc1 + w1*va;
    o1b = o1b*sc1 + w1*vb;
    m1 = mn1;
  }
  if (lane == 0) { wm[wv][0] = m0; wm[wv][1] = m1; wl[wv][0] = l0; wl[wv][1] = l1; }
  oc[g][o] = 0.f;
  __syncthreads();
  float M0 = fmaxf(fmaxf(wm[0][0], wm[1][0]), fmaxf(wm[2][0], wm[3][0]));
  float M1 = fmaxf(fmaxf(wm[0][1], wm[1][1]), fmaxf(wm[2][1], wm[3][1]));
  float f0 = __expf(m0 - M0);
  float f1 = __expf(m1 - M1);
  for (int w = 0; w < 4; w++) {           // deterministic cross-wave combine
    if (wv == w) {
      oc[0][lane*2]   += o0a*f0;
      oc[0][lane*2+1] += o0b*f0;
      oc[1][lane*2]   += o1a*f1;
      oc[1][lane*2+1] += o1b*f1;
    }
    __syncthreads();
  }
  float LL0 = wl[0][0]*__expf(wm[0][0]-M0) + wl[1][0]*__expf(wm[1][0]-M0)
            + wl[2][0]*__expf(wm[2][0]-M0) + wl[3][0]*__expf(wm[3][0]-M0);
  float LL1 = wl[0][1]*__expf(wm[0][1]-M1) + wl[1][1]*__expf(wm[1][1]-M1)
            + wl[2][1]*__expf(wm[2][1]-M1) + wl[3][1]*__expf(wm[3][1]-M1);
  int base = ((b*NHKV + kv)*NG + g)*S2 + chunk;
  if (o == 0) {
    ws[OFF_AM + base] = (g ? M1 : M0);
    ws[OFF_AL + base] = (g ? LL1 : LL0);
  }
  ws[OFF_AO + (size_t)base*HDIM + o] = oc[g][o];
}

// ---------------- K3: softmax-combine + Wo GEMV partials ----------------------
// grid (32 col-tiles, S3 d-splits), 256 threads
__global__ __launch_bounds__(256) void k3_wo(const float* __restrict__ Wo_,
    float* __restrict__ ws, int l)
{
  int ot = blockIdx.x;   // 0..31: cols [ot*32, +32)
  int s3 = blockIdx.y;   // 0..7 : i-range [s3*256, +256) == heads {2*s3, 2*s3+1}
  int tid = threadIdx.x;
  __shared__ float x[NB][256];
  __shared__ float wf[NB][2][S2];
  __shared__ float invL[NB][2];
  __shared__ float red[512];
  int h0 = s3*2;
  if (tid < 4) {
    int b = tid >> 1, hh = tid & 1;
    int hq = h0 + hh, kvh = hq >> 1, gg = hq & 1;
    const float* mp = ws + OFF_AM + ((b*NHKV + kvh)*NG + gg)*S2;
    const float* lp = ws + OFF_AL + ((b*NHKV + kvh)*NG + gg)*S2;
    float M = -1e30f;
    for (int c = 0; c < S2; c++) M = fmaxf(M, mp[c]);
    float Lx = 0.f;
    for (int c = 0; c < S2; c++) { float f = __expf(mp[c]-M); wf[b][hh][c] = f; Lx += lp[c]*f; }
    invL[b][hh] = 1.0f/Lx;
  }
  __syncthreads();
  for (int e = tid; e < 512; e += 256) {
    int b = e >> 8, r = e & 255, hh = r >> 7, dd = r & 127;
    int hq = h0 + hh, kvh = hq >> 1, gg = hq & 1;
    const float* op = ws + OFF_AO + (size_t)(((b*NHKV + kvh)*NG + gg)*S2)*HDIM + dd;
    float acc = 0.f;
    for (int c = 0; c < S2; c++) acc += op[(size_t)c*HDIM]*wf[b][hh][c];
    x[b][r] = acc*invL[b][hh];
  }
  __syncthreads();
  int o = tid & 31, ids = tid >> 5;
  int col = ot*32 + o;
  int dloc = ids*32;
  const float* Wp = Wo_ + (size_t)l*(NHQ*HDIM)*DIM + (size_t)(s3*256 + dloc)*DIM + col;
  float a0 = 0.f, a1 = 0.f;
  #pragma unroll 8
  for (int jj = 0; jj < 32; jj++) {
    float w = Wp[(size_t)jj*DIM];
    a0 += x[0][dloc+jj]*w;
    a1 += x[1][dloc+jj]*w;
  }
  red[tid] = a0; red[256+tid] = a1;
  __syncthreads();
  for (int off = 128; off >= 32; off >>= 1) {
    if (tid < off) { red[tid] += red[tid+off]; red[256+tid] += red[256+tid+off]; }
    __syncthreads();
  }
  if (tid < 32) {
    ws[OFF_WO + (s3*NB + 0)*DIM + col] = red[tid];
    ws[OFF_WO + (s3*NB + 1)*DIM + col] = red[256+tid];
  }
}

// ---------------- K4: h1 = h + Σwo_p, rmsnorm2, Wg/Wu GEMV partials -----------
// grid (48 col-tiles, S4 d-splits), 256 threads
__global__ __launch_bounds__(256) void k4_mlp1(const float* __restrict__ Wg_,
    const float* __restrict__ Wu_, const float* __restrict__ ln2,
    float* __restrict__ ws, int l)
{
  int ot = blockIdx.x;   // 0..47
  int s4 = blockIdx.y;   // 0..3
  int tid = threadIdx.x;
  __shared__ float sh[NB*DIM];
  __shared__ float red[512];
  float s0 = 0.f, sB = 0.f;
  for (int k = 0; k < 8; k++) {
    int idx = tid + k*256;
    int b = idx >> 10, d = idx & 1023;
    float v = ws[OFF_H + idx];
    #pragma unroll
    for (int s = 0; s < S3; s++) v += ws[OFF_WO + (s*NB + b)*DIM + d];
    sh[idx] = v;
    if (b == 0) s0 += v*v; else sB += v*v;
  }
  red[tid] = s0; red[256+tid] = sB;
  __syncthreads();
  for (int off = 128; off > 0; off >>= 1) {
    if (tid < off) { red[tid] += red[tid+off]; red[256+tid] += red[256+tid+off]; }
    __syncthreads();
  }
  float r0 = rsqrtf(red[0]/DIM + EPSF);
  float r1 = rsqrtf(red[256]/DIM + EPSF);
  for (int k = 0; k < 8; k++) {
    int idx = tid + k*256;
    int b = idx >> 10, d = idx & 1023;
    float v = sh[idx];
    if (ot == 0 && s4 == 0) ws[OFF_H1 + idx] = v;   // materialize h1
    sh[idx] = v * (b ? r1 : r0) * ln2[l*DIM + d];
  }
  __syncthreads();
  int o = tid & 63, ids = tid >> 6;
  int col = ot*64 + o;
  int dbase = s4*256 + ids*64;
  const float* Wgp = Wg_ + (size_t)l*DIM*NFF + (size_t)dbase*NFF + col;
  const float* Wup = Wu_ + (size_t)l*DIM*NFF + (size_t)dbase*NFF + col;
  float g0 = 0.f, g1 = 0.f, u0 = 0.f, u1 = 0.f;
  #pragma unroll 4
  for (int jj = 0; jj < 64; jj++) {
    float wg = Wgp[(size_t)jj*NFF], wu = Wup[(size_t)jj*NFF];
    float n0 = sh[dbase+jj], n1 = sh[DIM+dbase+jj];
    g0 += n0*wg; g1 += n1*wg; u0 += n0*wu; u1 += n1*wu;
  }
  red[tid] = g0; red[256+tid] = g1;
  __syncthreads();
  for (int off = 128; off >= 64; off >>= 1) {
    if (tid < off) { red[tid] += red[tid+off]; red[256+tid] += red[256+tid+off]; }
    __syncthreads();
  }
  if (tid < 64) {
    ws[OFF_G + (s4*NB + 0)*NFF + col] = red[tid];
    ws[OFF_G + (s4*NB + 1)*NFF + col] = red[256+tid];
  }
  __syncthreads();
  red[tid] = u0; red[256+tid] = u1;
  __syncthreads();
  for (int off = 128; off >= 64; off >>= 1) {
    if (tid < off) { red[tid] += red[tid+off]; red[256+tid] += red[256+tid+off]; }
    __syncthreads();
  }
  if (tid < 64) {
    ws[OFF_U + (s4*NB + 0)*NFF + col] = red[tid];
    ws[OFF_U + (s4*NB + 1)*NFF + col] = red[256+tid];
  }
}

// ---------------- K5: swiglu + Wd GEMV partials -------------------------------
// grid (32 col-tiles, S5 ff-splits), 256 threads
__global__ __launch_bounds__(256) void k5_mlp2(const float* __restrict__ Wd_,
    float* __restrict__ ws, int l)
{
  int ot = blockIdx.x;   // 0..31
  int s5 = blockIdx.y;   // 0..7 : ff-range [s5*384, +384)
  int tid = threadIdx.x;
  __shared__ float act[NB][384];
  __shared__ float red[512];
  int fbase = s5*384;
  for (int e = tid; e < 768; e += 256) {
    int b = (e >= 384);
    int loc = e - b*384;
    int ff = fbase + loc;
    float gv = 0.f, uv = 0.f;
    #pragma unroll
    for (int s = 0; s < S4; s++) {
      gv += ws[OFF_G + (s*NB + b)*NFF + ff];
      uv += ws[OFF_U + (s*NB + b)*NFF + ff];
    }
    float sg = gv / (1.0f + __expf(-gv));
    act[b][loc] = sg*uv;
  }
  __syncthreads();
  int o = tid & 31, ids = tid >> 5;
  int col = ot*32 + o;
  const float* Wp = Wd_ + (size_t)l*NFF*DIM + (size_t)(fbase + ids*48)*DIM + col;
  float a0 = 0.f, a1 = 0.f;
  #pragma unroll 4
  for (int jj = 0; jj < 48; jj++) {
    float w = Wp[(size_t)jj*DIM];
    a0 += act[0][ids*48+jj]*w;
    a1 += act[1][ids*48+jj]*w;
  }
  red[tid] = a0; red[256+tid] = a1;
  __syncthreads();
  for (int off = 128; off >= 32; off >>= 1) {
    if (tid < off) { red[tid] += red[tid+off]; red[256+tid] += red[256+tid+off]; }
    __syncthreads();
  }
  if (tid < 32) {
    ws[OFF_WD + (s5*NB + 0)*DIM + col] = red[tid];
    ws[OFF_WD + (s5*NB + 1)*DIM + col] = red[256+tid];
  }
}

// ---------------- K6: final rmsnorm + lm_head GEMV ----------------------------
// grid ceil(VOCAB/256), 256 threads
__global__ __launch_bounds__(256) void k6_lmhead(const float* __restrict__ lmw,
    const float* __restrict__ fnw, const float* __restrict__ ws,
    float* __restrict__ out)
{
  __shared__ float nf[NB*DIM];
  __shared__ float red[512];
  int tid = threadIdx.x;
  float s0 = 0.f, sB = 0.f;
  float hv[8];
  for (int k = 0; k < 8; k++) {
    int idx = tid + k*256;
    int b = idx >> 10, d = idx & 1023;
    float v = ws[OFF_H1 + idx];
    #pragma unroll
    for (int s = 0; s < S5; s++) v += ws[OFF_WD + (s*NB + b)*DIM + d];
    hv[k] = v;
    if (b == 0) s0 += v*v; else sB += v*v;
  }
  red[tid] = s0; red[256+tid] = sB;
  __syncthreads();
  for (int off = 128; off > 0; off >>= 1) {
    if (tid < off) { red[tid] += red[tid+off]; red[256+tid] += red[256+tid+off]; }
    __syncthreads();
  }
  float r0 = rsqrtf(red[0]/DIM + EPSF);
  float r1 = rsqrtf(red[256]/DIM + EPSF);
  for (int k = 0; k < 8; k++) {
    int idx = tid + k*256;
    int b = idx >> 10, d = idx & 1023;
    nf[idx] = hv[k] * (b ? r1 : r0) * fnw[d];
  }
  __syncthreads();
  int col = blockIdx.x*256 + tid;
  if (col < NVOCAB) {
    const float* Wp = lmw + col;
    float a0 = 0.f, a1 = 0.f;
    #pragma unroll 8
    for (int d = 0; d < DIM; d++) {
      float w = Wp[(size_t)d*NVOCAB];
      a0 += nf[d]*w;
      a1 += nf[DIM+d]*w;
    }
    out[col] = a0;
    out[NVOCAB + col] = a1;
  }
}

extern "C" void kernel_launch(void* const* d_in, const int* in_sizes, int n_in,
                              void* d_out, int out_size, void* d_ws, size_t ws_size,
                              hipStream_t stream) {
  (void)in_sizes; (void)n_in; (void)out_size; (void)ws_size;
  const float* embeds = (const float*)d_in[0];
  const int*   posids = (const int*)d_in[1];
  const float* pastK  = (const float*)d_in[2];
  const float* pastV  = (const float*)d_in[3];
  const float* Wq     = (const float*)d_in[4];
  const float* Wk     = (const float*)d_in[5];
  const float* Wv     = (const float*)d_in[6];
  const float* Wo     = (const float*)d_in[7];
  const float* Wg     = (const float*)d_in[8];
  const float* Wu     = (const float*)d_in[9];
  const float* Wd     = (const float*)d_in[10];
  const float* ln1    = (const float*)d_in[11];
  const float* ln2    = (const float*)d_in[12];
  const float* qnw    = (const float*)d_in[13];
  const float* knw    = (const float*)d_in[14];
  const float* fnw    = (const float*)d_in[15];
  const float* lmw    = (const float*)d_in[16];
  float* out = (float*)d_out;
  float* ws  = (float*)d_ws;

  for (int l = 0; l < NL; l++) {
    k1_qkv <<<dim3(32, S1), 256, 0, stream>>>(embeds, Wq, Wk, Wv, ln1, ws, l);
    k2_attn<<<dim3(S2, NHKV, NB), 256, 0, stream>>>(pastK, pastV, posids, qnw, knw, out, ws, l);
    k3_wo  <<<dim3(32, S3), 256, 0, stream>>>(Wo, ws, l);
    k4_mlp1<<<dim3(48, S4), 256, 0, stream>>>(Wg, Wu, ln2, ws, l);
    k5_mlp2<<<dim3(32, S5), 256, 0, stream>>>(Wd, ws, l);
  }
  k6_lmhead<<<(NVOCAB + 255)/256, 256, 0, stream>>>(lmw, fnw, ws, out);
}

// Round 2
// 1677.382 us; speedup vs baseline: 1.1244x; 1.1244x over previous
//
#include <hip/hip_runtime.h>
#include <math.h>

#define NL 28
#define DIM 1024
#define NHQ 16
#define NHKV 8
#define HDIM 128
#define NG 2
#define NFF 3072
#define NVOCAB 151936
#define NB 2
#define NPAST 1024
#define NPTOT 1025
#define EPSF 1e-6f
#define QKSCALE 0.08838834764831845f
#define LOGTHETA 13.815510557964274f

#define SQKV 16
#define SCH 32
#define SWO 16
#define SGU 8
#define SWD 16

// ws offsets (floats)
#define OFF_H   0
#define OFF_H1  2048
#define OFF_QKV 4096            // [16][NB][4096]
#define OFF_AM  135168          // [NB][NHKV][NG][32]
#define OFF_AL  136192
#define OFF_AO  137216          // [NB][NHKV][NG][32][128]
#define OFF_WO  268288          // [16][NB][1024]
#define OFF_G   301056          // [8][NB][3072]
#define OFF_U   350208
#define OFF_WD  399360          // [16][NB][1024]

#define PK_OFF ((size_t)NB*NVOCAB)
#define PV_OFF (PK_OFF + (size_t)NL*NB*NHKV*NPTOT*HDIM)

// ---------------- K1: rmsnorm(h) + QKV GEMV, float4, split-K=16 ---------------
// grid (16 colTiles(256), 16 dTiles(64)), 256 threads
__global__ __launch_bounds__(256) void k1_qkv(
    const float* __restrict__ embeds, const float* __restrict__ Wq_,
    const float* __restrict__ Wk_, const float* __restrict__ Wv_,
    const float* __restrict__ ln1, float* __restrict__ ws, int l)
{
  int bx = blockIdx.x, by = blockIdx.y;
  int tid = threadIdx.x;
  __shared__ __align__(16) float sh[NB*DIM];
  __shared__ __align__(16) float red[256*9];
  float s0 = 0.f, sB = 0.f;
  for (int k = 0; k < 8; k++) {
    int idx = tid + k*256;
    int b = idx >> 10, d = idx & 1023;
    float v;
    if (l == 0) v = embeds[idx];
    else {
      v = ws[OFF_H1 + idx];
      #pragma unroll
      for (int s = 0; s < SWD; s++) v += ws[OFF_WD + (s*NB + b)*DIM + d];
    }
    sh[idx] = v;
    if (b == 0) s0 += v*v; else sB += v*v;
  }
  red[tid] = s0; red[256+tid] = sB;
  __syncthreads();
  for (int off = 128; off > 0; off >>= 1) {
    if (tid < off) { red[tid] += red[tid+off]; red[256+tid] += red[256+tid+off]; }
    __syncthreads();
  }
  float r0n = rsqrtf(red[0]/DIM + EPSF);
  float r1n = rsqrtf(red[256]/DIM + EPSF);
  __syncthreads();
  for (int k = 0; k < 8; k++) {
    int idx = tid + k*256;
    int b = idx >> 10, d = idx & 1023;
    float v = sh[idx];
    if (bx == 0 && by == 0) ws[OFF_H + idx] = v;
    sh[idx] = v * (b ? r1n : r0n) * ln1[l*DIM + d];
  }
  __syncthreads();
  int ct = tid & 63, ds = tid >> 6;
  int colg = bx*256 + ct*4;
  const float* W; int O, wcol;
  if (colg < 2048)      { W = Wq_; O = 2048; wcol = colg; }
  else if (colg < 3072) { W = Wk_; O = 1024; wcol = colg - 2048; }
  else                  { W = Wv_; O = 1024; wcol = colg - 3072; }
  int r0 = by*64 + ds*16;
  const float* Wp = W + (size_t)l*DIM*O + (size_t)r0*O + wcol;
  float a[2][4] = {};
  #pragma unroll
  for (int i = 0; i < 16; i++) {
    float4 w4 = *(const float4*)(Wp + (size_t)i*O);
    float x0 = sh[r0+i], x1 = sh[DIM+r0+i];
    a[0][0] += x0*w4.x; a[0][1] += x0*w4.y; a[0][2] += x0*w4.z; a[0][3] += x0*w4.w;
    a[1][0] += x1*w4.x; a[1][1] += x1*w4.y; a[1][2] += x1*w4.z; a[1][3] += x1*w4.w;
  }
  float* rp = red + tid*9;
  #pragma unroll
  for (int e = 0; e < 4; e++) { rp[e] = a[0][e]; rp[4+e] = a[1][e]; }
  __syncthreads();
  if (tid < 64) {
    float o[8] = {};
    #pragma unroll
    for (int j = 0; j < 4; j++) {
      const float* q = red + (size_t)(j*64 + tid)*9;
      #pragma unroll
      for (int e = 0; e < 8; e++) o[e] += q[e];
    }
    int cg = bx*256 + tid*4;
    #pragma unroll
    for (int e = 0; e < 4; e++) {
      ws[OFF_QKV + (by*NB + 0)*4096 + cg + e] = o[e];
      ws[OFF_QKV + (by*NB + 1)*4096 + cg + e] = o[4+e];
    }
  }
}

// ---------------- K2: qkv finalize + qknorm + rope + KV copy + chunk attention
// grid (32 chunks, NHKV, NB), 256 threads
__global__ __launch_bounds__(256) void k2_attn(
    const float* __restrict__ pastK, const float* __restrict__ pastV,
    const int* __restrict__ posids, const float* __restrict__ qnw,
    const float* __restrict__ knw, float* __restrict__ out,
    float* __restrict__ ws, int l)
{
  int c = blockIdx.x, kv = blockIdx.y, b = blockIdx.z;
  int tid = threadIdx.x;
  __shared__ __align__(16) float qf[NG][HDIM];
  __shared__ __align__(16) float kf[HDIM];
  __shared__ __align__(16) float vf[HDIM];
  __shared__ __align__(16) float pre[3*HDIM];
  __shared__ __align__(16) float po[8][NG][HDIM];
  __shared__ float red[256];
  __shared__ float pm[8][NG], pl[8][NG];

  int g = tid >> 7, o = tid & 127;
  int hq = kv*NG + g;
  float qraw = 0.f, kvraw = 0.f;
  #pragma unroll
  for (int s = 0; s < SQKV; s++) qraw += ws[OFF_QKV + (s*NB + b)*4096 + hq*HDIM + o];
  if (g == 0) {
    #pragma unroll
    for (int s = 0; s < SQKV; s++) kvraw += ws[OFF_QKV + (s*NB + b)*4096 + 2048 + kv*HDIM + o];
  } else {
    #pragma unroll
    for (int s = 0; s < SQKV; s++) kvraw += ws[OFF_QKV + (s*NB + b)*4096 + 3072 + kv*HDIM + o];
  }
  red[tid] = qraw*qraw;
  __syncthreads();
  for (int off = 64; off > 0; off >>= 1) {
    if (o < off) red[tid] += red[tid+off];
    __syncthreads();
  }
  float qr = rsqrtf(red[g*128]/HDIM + EPSF);
  __syncthreads();
  red[tid] = (g == 0) ? kvraw*kvraw : 0.f;
  __syncthreads();
  for (int off = 128; off > 0; off >>= 1) {
    if (tid < off) red[tid] += red[tid+off];
    __syncthreads();
  }
  float kr = rsqrtf(red[0]/HDIM + EPSF);
  pre[g*HDIM + o] = qraw*qr*qnw[l*HDIM + o];
  if (g == 0) pre[2*HDIM + o] = kvraw*kr*knw[l*HDIM + o];
  else vf[o] = kvraw;
  __syncthreads();
  float pos = (float)posids[b];
  int j = o & 63;
  float ang = pos * expf(-(2.0f*(float)j/(float)HDIM)*LOGTHETA);
  float sn, cs;
  sincosf(ang, &sn, &cs);
  {
    float qv = pre[g*HDIM + o];
    float qo = (o < 64) ? -pre[g*HDIM + o + 64] : pre[g*HDIM + o - 64];
    qf[g][o] = qv*cs + qo*sn;
    if (g == 0) {
      float kx = pre[2*HDIM + o];
      float ko = (o < 64) ? -pre[2*HDIM + o + 64] : pre[2*HDIM + o - 64];
      kf[o] = kx*cs + ko*sn;
    }
  }
  __syncthreads();

  int lane = tid & 63, w = tid >> 6;
  int h = (lane >> 5) & 1, q = lane & 31;
  int grp = w*2 + h;
  int p0 = c*32;
  int p1 = (c == SCH-1) ? NPTOT : p0 + 32;
  size_t pastbase = ((((size_t)l*NB + b)*NHKV + kv)*NPAST)*HDIM;
  size_t presbase = ((((size_t)l*NB + b)*NHKV + kv)*NPTOT)*HDIM;
  float4 q0 = *(const float4*)&qf[0][q*4];
  float4 q1 = *(const float4*)&qf[1][q*4];
  float sc0[5], sc1[5];
  float4 vv[5];
  int ns = 0;
  for (int p = p0 + grp; p < p1; p += 8) {
    float4 k4, v4;
    if (p < NPAST) {
      k4 = *(const float4*)(pastK + pastbase + (size_t)p*HDIM + q*4);
      v4 = *(const float4*)(pastV + pastbase + (size_t)p*HDIM + q*4);
    } else {
      k4 = *(const float4*)&kf[q*4];
      v4 = *(const float4*)&vf[q*4];
    }
    *(float4*)(out + PK_OFF + presbase + (size_t)p*HDIM + q*4) = k4;
    *(float4*)(out + PV_OFF + presbase + (size_t)p*HDIM + q*4) = v4;
    float d0 = q0.x*k4.x + q0.y*k4.y + q0.z*k4.z + q0.w*k4.w;
    float d1 = q1.x*k4.x + q1.y*k4.y + q1.z*k4.z + q1.w*k4.w;
    #pragma unroll
    for (int off = 16; off > 0; off >>= 1) {
      d0 += __shfl_xor(d0, off);
      d1 += __shfl_xor(d1, off);
    }
    sc0[ns] = d0*QKSCALE; sc1[ns] = d1*QKSCALE; vv[ns] = v4; ns++;
  }
  float m0 = -1e30f, m1 = -1e30f;
  for (int i = 0; i < ns; i++) { m0 = fmaxf(m0, sc0[i]); m1 = fmaxf(m1, sc1[i]); }
  if (q == 0) { pm[grp][0] = m0; pm[grp][1] = m1; }
  __syncthreads();
  float M0 = -1e30f, M1 = -1e30f;
  #pragma unroll
  for (int i = 0; i < 8; i++) { M0 = fmaxf(M0, pm[i][0]); M1 = fmaxf(M1, pm[i][1]); }
  float l0 = 0.f, l1 = 0.f;
  float4 o0 = {0,0,0,0}, o1 = {0,0,0,0};
  for (int i = 0; i < ns; i++) {
    float w0 = __expf(sc0[i] - M0), w1 = __expf(sc1[i] - M1);
    l0 += w0; l1 += w1;
    o0.x += w0*vv[i].x; o0.y += w0*vv[i].y; o0.z += w0*vv[i].z; o0.w += w0*vv[i].w;
    o1.x += w1*vv[i].x; o1.y += w1*vv[i].y; o1.z += w1*vv[i].z; o1.w += w1*vv[i].w;
  }
  if (q == 0) { pl[grp][0] = l0; pl[grp][1] = l1; }
  *(float4*)&po[grp][0][q*4] = o0;
  *(float4*)&po[grp][1][q*4] = o1;
  __syncthreads();
  {
    int head = tid >> 7, dd = tid & 127;
    float acc = 0.f;
    #pragma unroll
    for (int i = 0; i < 8; i++) acc += po[i][head][dd];
    int base = ((b*NHKV + kv)*NG + head)*SCH + c;
    ws[OFF_AO + (size_t)base*HDIM + dd] = acc;
    if (dd == 0) {
      float ll = 0.f;
      #pragma unroll
      for (int i = 0; i < 8; i++) ll += pl[i][head];
      ws[OFF_AM + base] = (head ? M1 : M0);
      ws[OFF_AL + base] = ll;
    }
  }
}

// ---------------- K3: softmax combine + Wo GEMV, float4 -----------------------
// grid (16 colTiles(64), 16 heads), 256 threads
__global__ __launch_bounds__(256) void k3_wo(const float* __restrict__ Wo_,
    float* __restrict__ ws, int l)
{
  int bx = blockIdx.x, head = blockIdx.y;
  int tid = threadIdx.x;
  __shared__ __align__(16) float x[NB][HDIM];
  __shared__ float wf[NB][SCH];
  __shared__ float invL[NB];
  __shared__ __align__(16) float red[256*9];
  int kvh = head >> 1, gg = head & 1;
  if (tid < NB) {
    int b = tid;
    const float* mp = ws + OFF_AM + ((b*NHKV + kvh)*NG + gg)*SCH;
    const float* lp = ws + OFF_AL + ((b*NHKV + kvh)*NG + gg)*SCH;
    float M = -1e30f;
    for (int cc = 0; cc < SCH; cc++) M = fmaxf(M, mp[cc]);
    float L = 0.f;
    for (int cc = 0; cc < SCH; cc++) { float f = __expf(mp[cc]-M); wf[b][cc] = f; L += lp[cc]*f; }
    invL[b] = 1.0f/L;
  }
  __syncthreads();
  {
    int b = tid >> 7, dd = tid & 127;
    const float* op = ws + OFF_AO + (size_t)(((b*NHKV + kvh)*NG + gg)*SCH)*HDIM + dd;
    float acc = 0.f;
    for (int cc = 0; cc < SCH; cc++) acc += op[(size_t)cc*HDIM]*wf[b][cc];
    x[b][dd] = acc*invL[b];
  }
  __syncthreads();
  int ct = tid & 15, ds = tid >> 4;
  int col = bx*64 + ct*4;
  int r0 = ds*8;
  const float* Wp = Wo_ + (size_t)l*(NHQ*HDIM)*DIM + (size_t)(head*HDIM + r0)*DIM + col;
  float a[2][4] = {};
  #pragma unroll
  for (int i = 0; i < 8; i++) {
    float4 w4 = *(const float4*)(Wp + (size_t)i*DIM);
    float x0 = x[0][r0+i], x1 = x[1][r0+i];
    a[0][0] += x0*w4.x; a[0][1] += x0*w4.y; a[0][2] += x0*w4.z; a[0][3] += x0*w4.w;
    a[1][0] += x1*w4.x; a[1][1] += x1*w4.y; a[1][2] += x1*w4.z; a[1][3] += x1*w4.w;
  }
  float* rp = red + tid*9;
  #pragma unroll
  for (int e = 0; e < 4; e++) { rp[e] = a[0][e]; rp[4+e] = a[1][e]; }
  __syncthreads();
  if (tid < 16) {
    float o[8] = {};
    #pragma unroll
    for (int jj = 0; jj < 16; jj++) {
      const float* qq = red + (size_t)(jj*16 + tid)*9;
      #pragma unroll
      for (int e = 0; e < 8; e++) o[e] += qq[e];
    }
    int cg = bx*64 + tid*4;
    #pragma unroll
    for (int e = 0; e < 4; e++) {
      ws[OFF_WO + (head*NB + 0)*DIM + cg + e] = o[e];
      ws[OFF_WO + (head*NB + 1)*DIM + cg + e] = o[4+e];
    }
  }
}

// ---------------- K4: h1 + rmsnorm2 + Wg/Wu GEMV, float4 ----------------------
// grid (48 colTiles(64), 8 dTiles(128)), 256 threads
__global__ __launch_bounds__(256) void k4_mlp1(const float* __restrict__ Wg_,
    const float* __restrict__ Wu_, const float* __restrict__ ln2,
    float* __restrict__ ws, int l)
{
  int bx = blockIdx.x, by = blockIdx.y;
  int tid = threadIdx.x;
  __shared__ __align__(16) float sh[NB*DIM];
  __shared__ __align__(16) float red[256*9];
  float s0 = 0.f, sB = 0.f;
  for (int k = 0; k < 8; k++) {
    int idx = tid + k*256;
    int b = idx >> 10, d = idx & 1023;
    float v = ws[OFF_H + idx];
    #pragma unroll
    for (int s = 0; s < SWO; s++) v += ws[OFF_WO + (s*NB + b)*DIM + d];
    sh[idx] = v;
    if (b == 0) s0 += v*v; else sB += v*v;
  }
  red[tid] = s0; red[256+tid] = sB;
  __syncthreads();
  for (int off = 128; off > 0; off >>= 1) {
    if (tid < off) { red[tid] += red[tid+off]; red[256+tid] += red[256+tid+off]; }
    __syncthreads();
  }
  float r0n = rsqrtf(red[0]/DIM + EPSF);
  float r1n = rsqrtf(red[256]/DIM + EPSF);
  __syncthreads();
  for (int k = 0; k < 8; k++) {
    int idx = tid + k*256;
    int b = idx >> 10, d = idx & 1023;
    float v = sh[idx];
    if (bx == 0 && by == 0) ws[OFF_H1 + idx] = v;
    sh[idx] = v * (b ? r1n : r0n) * ln2[l*DIM + d];
  }
  __syncthreads();
  int ct = tid & 15, ds = tid >> 4;
  int col = bx*64 + ct*4;
  int r0 = by*128 + ds*8;
  const float* Wgp = Wg_ + (size_t)l*DIM*NFF + (size_t)r0*NFF + col;
  const float* Wup = Wu_ + (size_t)l*DIM*NFF + (size_t)r0*NFF + col;
  float ag[2][4] = {}, au[2][4] = {};
  #pragma unroll
  for (int i = 0; i < 8; i++) {
    float4 wg = *(const float4*)(Wgp + (size_t)i*NFF);
    float4 wu = *(const float4*)(Wup + (size_t)i*NFF);
    float x0 = sh[r0+i], x1 = sh[DIM+r0+i];
    ag[0][0] += x0*wg.x; ag[0][1] += x0*wg.y; ag[0][2] += x0*wg.z; ag[0][3] += x0*wg.w;
    ag[1][0] += x1*wg.x; ag[1][1] += x1*wg.y; ag[1][2] += x1*wg.z; ag[1][3] += x1*wg.w;
    au[0][0] += x0*wu.x; au[0][1] += x0*wu.y; au[0][2] += x0*wu.z; au[0][3] += x0*wu.w;
    au[1][0] += x1*wu.x; au[1][1] += x1*wu.y; au[1][2] += x1*wu.z; au[1][3] += x1*wu.w;
  }
  float* rp = red + tid*9;
  #pragma unroll
  for (int e = 0; e < 4; e++) { rp[e] = ag[0][e]; rp[4+e] = ag[1][e]; }
  __syncthreads();
  if (tid < 16) {
    float o[8] = {};
    #pragma unroll
    for (int jj = 0; jj < 16; jj++) {
      const float* qq = red + (size_t)(jj*16 + tid)*9;
      #pragma unroll
      for (int e = 0; e < 8; e++) o[e] += qq[e];
    }
    int cg = bx*64 + tid*4;
    #pragma unroll
    for (int e = 0; e < 4; e++) {
      ws[OFF_G + (by*NB + 0)*NFF + cg + e] = o[e];
      ws[OFF_G + (by*NB + 1)*NFF + cg + e] = o[4+e];
    }
  }
  __syncthreads();
  #pragma unroll
  for (int e = 0; e < 4; e++) { rp[e] = au[0][e]; rp[4+e] = au[1][e]; }
  __syncthreads();
  if (tid < 16) {
    float o[8] = {};
    #pragma unroll
    for (int jj = 0; jj < 16; jj++) {
      const float* qq = red + (size_t)(jj*16 + tid)*9;
      #pragma unroll
      for (int e = 0; e < 8; e++) o[e] += qq[e];
    }
    int cg = bx*64 + tid*4;
    #pragma unroll
    for (int e = 0; e < 4; e++) {
      ws[OFF_U + (by*NB + 0)*NFF + cg + e] = o[e];
      ws[OFF_U + (by*NB + 1)*NFF + cg + e] = o[4+e];
    }
  }
}

// ---------------- K5: swiglu + Wd GEMV, float4 --------------------------------
// grid (16 colTiles(64), 16 ffTiles(192)), 256 threads
__global__ __launch_bounds__(256) void k5_mlp2(const float* __restrict__ Wd_,
    float* __restrict__ ws, int l)
{
  int bx = blockIdx.x, by = blockIdx.y;
  int tid = threadIdx.x;
  __shared__ __align__(16) float act[NB][192];
  __shared__ __align__(16) float red[256*9];
  int fbase = by*192;
  for (int e = tid; e < 384; e += 256) {
    int b = (e >= 192);
    int loc = e - b*192;
    int ff = fbase + loc;
    float gv = 0.f, uv = 0.f;
    #pragma unroll
    for (int s = 0; s < SGU; s++) {
      gv += ws[OFF_G + (s*NB + b)*NFF + ff];
      uv += ws[OFF_U + (s*NB + b)*NFF + ff];
    }
    act[b][loc] = (gv / (1.0f + __expf(-gv)))*uv;
  }
  __syncthreads();
  int ct = tid & 15, ds = tid >> 4;
  int col = bx*64 + ct*4;
  int loc0 = ds*12;
  const float* Wp = Wd_ + (size_t)l*NFF*DIM + (size_t)(fbase + loc0)*DIM + col;
  float a[2][4] = {};
  #pragma unroll
  for (int i = 0; i < 12; i++) {
    float4 w4 = *(const float4*)(Wp + (size_t)i*DIM);
    float x0 = act[0][loc0+i], x1 = act[1][loc0+i];
    a[0][0] += x0*w4.x; a[0][1] += x0*w4.y; a[0][2] += x0*w4.z; a[0][3] += x0*w4.w;
    a[1][0] += x1*w4.x; a[1][1] += x1*w4.y; a[1][2] += x1*w4.z; a[1][3] += x1*w4.w;
  }
  float* rp = red + tid*9;
  #pragma unroll
  for (int e = 0; e < 4; e++) { rp[e] = a[0][e]; rp[4+e] = a[1][e]; }
  __syncthreads();
  if (tid < 16) {
    float o[8] = {};
    #pragma unroll
    for (int jj = 0; jj < 16; jj++) {
      const float* qq = red + (size_t)(jj*16 + tid)*9;
      #pragma unroll
      for (int e = 0; e < 8; e++) o[e] += qq[e];
    }
    int cg = bx*64 + tid*4;
    #pragma unroll
    for (int e = 0; e < 4; e++) {
      ws[OFF_WD + (by*NB + 0)*DIM + cg + e] = o[e];
      ws[OFF_WD + (by*NB + 1)*DIM + cg + e] = o[4+e];
    }
  }
}

// ---------------- K6: final rmsnorm + lm_head GEMV, float4 --------------------
// grid 594, 256 threads
__global__ __launch_bounds__(256) void k6_lmhead(const float* __restrict__ lmw,
    const float* __restrict__ fnw, const float* __restrict__ ws,
    float* __restrict__ out)
{
  __shared__ __align__(16) float nf[NB*DIM];
  __shared__ __align__(16) float red[256*9];
  int tid = threadIdx.x;
  float s0 = 0.f, sB = 0.f;
  float hv[8];
  for (int k = 0; k < 8; k++) {
    int idx = tid + k*256;
    int b = idx >> 10, d = idx & 1023;
    float v = ws[OFF_H1 + idx];
    #pragma unroll
    for (int s = 0; s < SWD; s++) v += ws[OFF_WD + (s*NB + b)*DIM + d];
    hv[k] = v;
    if (b == 0) s0 += v*v; else sB += v*v;
  }
  red[tid] = s0; red[256+tid] = sB;
  __syncthreads();
  for (int off = 128; off > 0; off >>= 1) {
    if (tid < off) { red[tid] += red[tid+off]; red[256+tid] += red[256+tid+off]; }
    __syncthreads();
  }
  float r0n = rsqrtf(red[0]/DIM + EPSF);
  float r1n = rsqrtf(red[256]/DIM + EPSF);
  __syncthreads();
  for (int k = 0; k < 8; k++) {
    int idx = tid + k*256;
    int b = idx >> 10, d = idx & 1023;
    nf[idx] = hv[k] * (b ? r1n : r0n) * fnw[d];
  }
  __syncthreads();
  int ct = tid & 63, ds = tid >> 6;
  int quad = blockIdx.x*64 + ct;
  int valid = quad < (NVOCAB/4);
  int col = quad*4;
  float a[2][4] = {};
  if (valid) {
    const float* Wp = lmw + (size_t)(ds*256)*NVOCAB + col;
    for (int i = 0; i < 256; i++) {
      float4 w4 = *(const float4*)(Wp + (size_t)i*NVOCAB);
      float x0 = nf[ds*256+i], x1 = nf[DIM+ds*256+i];
      a[0][0] += x0*w4.x; a[0][1] += x0*w4.y; a[0][2] += x0*w4.z; a[0][3] += x0*w4.w;
      a[1][0] += x1*w4.x; a[1][1] += x1*w4.y; a[1][2] += x1*w4.z; a[1][3] += x1*w4.w;
    }
  }
  float* rp = red + tid*9;
  #pragma unroll
  for (int e = 0; e < 4; e++) { rp[e] = a[0][e]; rp[4+e] = a[1][e]; }
  __syncthreads();
  if (tid < 64 && valid) {
    float o[8] = {};
    #pragma unroll
    for (int jj = 0; jj < 4; jj++) {
      const float* qq = red + (size_t)(jj*64 + tid)*9;
      #pragma unroll
      for (int e = 0; e < 8; e++) o[e] += qq[e];
    }
    #pragma unroll
    for (int e = 0; e < 4; e++) {
      out[col + e] = o[e];
      out[NVOCAB + col + e] = o[4+e];
    }
  }
}

extern "C" void kernel_launch(void* const* d_in, const int* in_sizes, int n_in,
                              void* d_out, int out_size, void* d_ws, size_t ws_size,
                              hipStream_t stream) {
  (void)in_sizes; (void)n_in; (void)out_size; (void)ws_size;
  const float* embeds = (const float*)d_in[0];
  const int*   posids = (const int*)d_in[1];
  const float* pastK  = (const float*)d_in[2];
  const float* pastV  = (const float*)d_in[3];
  const float* Wq     = (const float*)d_in[4];
  const float* Wk     = (const float*)d_in[5];
  const float* Wv     = (const float*)d_in[6];
  const float* Wo     = (const float*)d_in[7];
  const float* Wg     = (const float*)d_in[8];
  const float* Wu     = (const float*)d_in[9];
  const float* Wd     = (const float*)d_in[10];
  const float* ln1    = (const float*)d_in[11];
  const float* ln2    = (const float*)d_in[12];
  const float* qnw    = (const float*)d_in[13];
  const float* knw    = (const float*)d_in[14];
  const float* fnw    = (const float*)d_in[15];
  const float* lmw    = (const float*)d_in[16];
  float* out = (float*)d_out;
  float* ws  = (float*)d_ws;

  for (int l = 0; l < NL; l++) {
    k1_qkv <<<dim3(16, 16), 256, 0, stream>>>(embeds, Wq, Wk, Wv, ln1, ws, l);
    k2_attn<<<dim3(SCH, NHKV, NB), 256, 0, stream>>>(pastK, pastV, posids, qnw, knw, out, ws, l);
    k3_wo  <<<dim3(16, 16), 256, 0, stream>>>(Wo, ws, l);
    k4_mlp1<<<dim3(48, 8), 256, 0, stream>>>(Wg, Wu, ln2, ws, l);
    k5_mlp2<<<dim3(16, 16), 256, 0, stream>>>(Wd, ws, l);
  }
  k6_lmhead<<<(NVOCAB/4 + 63)/64, 256, 0, stream>>>(lmw, fnw, ws, out);
}